// Round 1
// baseline (833.247 us; speedup 1.0000x reference)
//
#include <hip/hip_runtime.h>
#include <math.h>

#define B 32
#define M 2048
#define H 1024
#define THRESH 0.99f

// ---------------------------------------------------------------------------
// Kernel 1: per-batch inclusive scan over `run` mask -> rank = clip(cumsum-1,0)
// 1 block per batch, 256 threads x 8 elements.
// ---------------------------------------------------------------------------
__global__ void k_rank(const int* __restrict__ run, int* __restrict__ rank) {
    int bb = blockIdx.x;
    int t  = threadIdx.x;            // 0..255
    const int* r = run + bb * M;
    int base = t * 8;
    int vals[8];
    int s = 0;
#pragma unroll
    for (int i = 0; i < 8; i++) { vals[i] = (r[base + i] != 0) ? 1 : 0; s += vals[i]; }

    int lane = t & 63, wid = t >> 6;
    int inc = s;
#pragma unroll
    for (int off = 1; off < 64; off <<= 1) {
        int y = __shfl_up(inc, off, 64);
        if (lane >= off) inc += y;
    }
    __shared__ int wsum[4];
    if (lane == 63) wsum[wid] = inc;
    __syncthreads();
    int woff = 0;
    for (int w = 0; w < wid; w++) woff += wsum[w];
    int c = woff + (inc - s);        // exclusive prefix for this thread
#pragma unroll
    for (int i = 0; i < 8; i++) {
        c += vals[i];
        int rk = c - 1;
        if (rk < 0) rk = 0;
        rank[bb * M + base + i] = rk;
    }
}

// ---------------------------------------------------------------------------
// Kernel 2: logits[b,m] = dot(h[b, rank[b,m], :], W)  for running tokens.
// 1 block (256 thr, float4 each) per token row.
// ---------------------------------------------------------------------------
__global__ void k_dot(const float* __restrict__ h, const float* __restrict__ W,
                      const int* __restrict__ run, const int* __restrict__ rank,
                      float* __restrict__ logits) {
    int blk = blockIdx.x;
    int bb = blk >> 11;              // / M
    int m  = blk & (M - 1);
    int idx = bb * M + m;
    if (run[idx] == 0) return;
    int t = threadIdx.x;
    const float4* row = (const float4*)(h + ((size_t)bb * M + rank[idx]) * H);
    const float4* wv4 = (const float4*)W;
    float4 hv = row[t];
    float4 wv = wv4[t];
    float d = hv.x * wv.x + hv.y * wv.y + hv.z * wv.z + hv.w * wv.w;
#pragma unroll
    for (int off = 32; off > 0; off >>= 1) d += __shfl_down(d, off, 64);
    __shared__ float ws4[4];
    int lane = t & 63, wid = t >> 6;
    if (lane == 0) ws4[wid] = d;
    __syncthreads();
    if (t == 0) logits[idx] = ws4[0] + ws4[1] + ws4[2] + ws4[3];
}

// ---------------------------------------------------------------------------
// Kernel 3: halting logic + scan over run_new -> newrank, counts; write acc_new.
// 1 block per batch, 256 threads x 8 elements.
// ---------------------------------------------------------------------------
__global__ void k_halt(const float* __restrict__ logits, const float* __restrict__ acc_p,
                       const int* __restrict__ run, const float* __restrict__ bptr,
                       float* __restrict__ acc_out, float* __restrict__ p_adj,
                       int* __restrict__ newrank, int* __restrict__ counts) {
    int bb = blockIdx.x;
    int t  = threadIdx.x;
    float bscalar = bptr[0];
    int base = bb * M + t * 8;
    int contv[8];
    int s = 0;
#pragma unroll
    for (int i = 0; i < 8; i++) {
        int idx = base + i;
        int rn = (run[idx] != 0);
        float ap = acc_p[idx];
        float p = 0.0f;
        if (rn) p = 1.0f / (1.0f + expf(-(logits[idx] + bscalar)));
        float an = ap + p;
        acc_out[idx] = an;
        int cont = rn && (an < THRESH);
        int ext  = rn && !cont;
        p_adj[idx] = cont ? p : (ext ? (1.0f - ap) : 0.0f);
        contv[i] = cont;
        s += cont;
    }
    int lane = t & 63, wid = t >> 6;
    int inc = s;
#pragma unroll
    for (int off = 1; off < 64; off <<= 1) {
        int y = __shfl_up(inc, off, 64);
        if (lane >= off) inc += y;
    }
    __shared__ int wsum[4];
    if (lane == 63) wsum[wid] = inc;
    __syncthreads();
    int woff = 0;
    for (int w = 0; w < wid; w++) woff += wsum[w];
    int c = woff + (inc - s);
#pragma unroll
    for (int i = 0; i < 8; i++) {
        c += contv[i];
        newrank[base + i] = contv[i] ? (c - 1) : -1;
    }
    if (t == 0) counts[bb] = wsum[0] + wsum[1] + wsum[2] + wsum[3];
}

// ---------------------------------------------------------------------------
// Kernel 4: elementwise pass. 1 block per (b,m) row, 256 threads x float4.
//   weighted_new = h_un * p_adj + weighted_h * (1 - p_adj)
//   packed[b, newrank, :] = h_un   (scatter, running-new rows)
//   packed[b, m, :] = 0 for m >= counts[b]
// ---------------------------------------------------------------------------
__global__ void k_elem(const float* __restrict__ h, const float* __restrict__ wh,
                       const int* __restrict__ run, const int* __restrict__ rank,
                       const float* __restrict__ p_adj, const int* __restrict__ newrank,
                       const int* __restrict__ counts,
                       float* __restrict__ packed, float* __restrict__ weighted) {
    int blk = blockIdx.x;
    int bb = blk >> 11;
    int m  = blk & (M - 1);
    int idx = bb * M + m;
    int t = threadIdx.x;
    size_t rowoff = (size_t)idx * H + (size_t)t * 4;

    float4 whv = *(const float4*)(wh + rowoff);
    int rn = (run[idx] != 0);
    if (rn) {
        float pa = p_adj[idx];
        const float* hrow = h + ((size_t)bb * M + rank[idx]) * H;
        float4 hv = *(const float4*)(hrow + (size_t)t * 4);
        float4 o;
        o.x = hv.x * pa + whv.x * (1.0f - pa);
        o.y = hv.y * pa + whv.y * (1.0f - pa);
        o.z = hv.z * pa + whv.z * (1.0f - pa);
        o.w = hv.w * pa + whv.w * (1.0f - pa);
        *(float4*)(weighted + rowoff) = o;
        int nr = newrank[idx];
        if (nr >= 0) {
            *(float4*)(packed + ((size_t)bb * M + nr) * H + (size_t)t * 4) = hv;
        }
    } else {
        *(float4*)(weighted + rowoff) = whv;
    }
    if (m >= counts[bb]) {
        float4 z = make_float4(0.0f, 0.0f, 0.0f, 0.0f);
        *(float4*)(packed + rowoff) = z;
    }
}

// ---------------------------------------------------------------------------
extern "C" void kernel_launch(void* const* d_in, const int* in_sizes, int n_in,
                              void* d_out, int out_size, void* d_ws, size_t ws_size,
                              hipStream_t stream) {
    const float* h    = (const float*)d_in[0];   // [B,M,H]
    const float* W    = (const float*)d_in[1];   // [1,H]
    const float* bptr = (const float*)d_in[2];   // [1]
    const float* wh   = (const float*)d_in[3];   // [B,M,H]
    const float* accp = (const float*)d_in[4];   // [B,M,1]
    const int*   run  = (const int*)d_in[5];     // [B,M,1] bool->int

    float* packed   = (float*)d_out;                       // [B,M,H]
    float* weighted = (float*)d_out + (size_t)B * M * H;   // [B,M,H]
    float* acc_out  = (float*)d_out + 2 * (size_t)B * M * H; // [B,M,1]

    int*   rank    = (int*)d_ws;                 // B*M
    float* logits  = (float*)d_ws + (size_t)B * M;
    float* padj    = (float*)d_ws + 2 * (size_t)B * M;
    int*   newrank = (int*)d_ws + 3 * (size_t)B * M;
    int*   counts  = (int*)d_ws + 4 * (size_t)B * M; // B

    k_rank<<<B, 256, 0, stream>>>(run, rank);
    k_dot<<<B * M, 256, 0, stream>>>(h, W, run, rank, logits);
    k_halt<<<B, 256, 0, stream>>>(logits, accp, run, bptr, acc_out, padj, newrank, counts);
    k_elem<<<B * M, 256, 0, stream>>>(h, wh, run, rank, padj, newrank, counts, packed, weighted);
}